// Round 4
// baseline (9207.539 us; speedup 1.0000x reference)
//
#include <hip/hip_runtime.h>
#include <cstddef>
#include <stdint.h>

// ---------------- problem constants ----------------
#define NHID 1024
#define NVOC 31
#define NB   64
#define NSEQ 512
#define NBLK 128     // 64 role0 (layer0) + 64 role2 (layer1 + xg)
#define NTHR 512     // 8 waves
#define EPSV 1e-5f
#define RS   68      // LDS reduce stride: 68*4B=272, 16B-aligned rows

typedef __attribute__((ext_vector_type(8))) short short8;   // 8 x bf16
typedef __attribute__((ext_vector_type(4))) float float4v;

// ---------------- workspace layout (bytes) ----------------
#define OFF_C0  0               // 513 slots (stride 64B): c0[t+1] = y0(t) ready
#define OFF_C2  65600           // 513 slots: c2[t+1] = h1(t) ready
#define OFF_D2  98432           // 512 slots: d2[t] = role2 consumed y0(t)
#define OFF_FIN 131200
#define CNT_BYTES 131264
#define OFF_Y0  131328          // y0 ring: 2 x [64][1024] bf16
#define OFF_H1  393472          // h1 ring: 2 x [64][1024] bf16
#define OFF_T0  2228480         // T0: [31][3072] f32 (role0-WG-private)
#define OFF_ST  2609408         // stats: [2][1024] f32
#define OFF_Y1  2617600         // y1: [512][64][1024] bf16 (64MB) -> total 69.7MB (proven fits)

// LDS: red = 192 rows x RS floats = 52224B; hpart = 128 thr x 25 floats = 12800B
#define LDS_HP_OFF 52224
#define LDS_BYTES  65024

__device__ __forceinline__ unsigned short f2bf(float f){
  unsigned u = __builtin_bit_cast(unsigned, f);
  u += 0x7fffu + ((u >> 16) & 1u);               // RNE
  return (unsigned short)(u >> 16);
}
__device__ __forceinline__ float bf2f(unsigned short h){
  unsigned u = ((unsigned)h) << 16;
  return __builtin_bit_cast(float, u);
}
__device__ __forceinline__ float sigm(float x){ return 1.f/(1.f + __expf(-x)); }
__device__ __forceinline__ float tanh_f(float x){ return 1.f - 2.f/(__expf(2.f*x) + 1.f); }

__device__ __forceinline__ void sig(unsigned* c){
  __hip_atomic_fetch_add(c, 1u, __ATOMIC_RELAXED, __HIP_MEMORY_SCOPE_AGENT);
}
__device__ __forceinline__ void waitc(unsigned* c, unsigned v){
  while (__hip_atomic_load(c, __ATOMIC_RELAXED, __HIP_MEMORY_SCOPE_AGENT) < v)
    __builtin_amdgcn_s_sleep(1);
}

// 16B agent-coherent store + drain (matches compiler's agent-scope atomic store: sc1)
__device__ __forceinline__ void stc16_drain(void* p, short8 v){
  asm volatile("global_store_dwordx4 %0, %1, off sc1\n\t"
               "s_waitcnt vmcnt(0)"
               :: "v"((unsigned long long)(uintptr_t)p), "v"(v) : "memory");
}

// Load 16 A-fragments (4 row-groups x 4 kt) of H via 16B agent-coherent loads.
// One asm block: 16 loads in flight, single vmcnt(0). EARLY-CLOBBER outputs:
// data returns must never land in the address registers (%16-%19).
__device__ __forceinline__ void load_a16(const unsigned short* base, short8 (&f)[4][4]){
  unsigned long long A0 = (unsigned long long)(uintptr_t)base;
  unsigned long long A1 = A0 + (unsigned long long)(16*NHID*2);
  unsigned long long A2 = A0 + (unsigned long long)(32*NHID*2);
  unsigned long long A3 = A0 + (unsigned long long)(48*NHID*2);
  asm volatile(
    "global_load_dwordx4 %0, %16, off sc1\n\t"
    "global_load_dwordx4 %1, %16, off offset:64 sc1\n\t"
    "global_load_dwordx4 %2, %16, off offset:128 sc1\n\t"
    "global_load_dwordx4 %3, %16, off offset:192 sc1\n\t"
    "global_load_dwordx4 %4, %17, off sc1\n\t"
    "global_load_dwordx4 %5, %17, off offset:64 sc1\n\t"
    "global_load_dwordx4 %6, %17, off offset:128 sc1\n\t"
    "global_load_dwordx4 %7, %17, off offset:192 sc1\n\t"
    "global_load_dwordx4 %8, %18, off sc1\n\t"
    "global_load_dwordx4 %9, %18, off offset:64 sc1\n\t"
    "global_load_dwordx4 %10, %18, off offset:128 sc1\n\t"
    "global_load_dwordx4 %11, %18, off offset:192 sc1\n\t"
    "global_load_dwordx4 %12, %19, off sc1\n\t"
    "global_load_dwordx4 %13, %19, off offset:64 sc1\n\t"
    "global_load_dwordx4 %14, %19, off offset:128 sc1\n\t"
    "global_load_dwordx4 %15, %19, off offset:192 sc1\n\t"
    "s_waitcnt vmcnt(0)"
    : "=&v"(f[0][0]), "=&v"(f[0][1]), "=&v"(f[0][2]), "=&v"(f[0][3]),
      "=&v"(f[1][0]), "=&v"(f[1][1]), "=&v"(f[1][2]), "=&v"(f[1][3]),
      "=&v"(f[2][0]), "=&v"(f[2][1]), "=&v"(f[2][2]), "=&v"(f[2][3]),
      "=&v"(f[3][0]), "=&v"(f[3][1]), "=&v"(f[3][2]), "=&v"(f[3][3])
    : "v"(A0), "v"(A1), "v"(A2), "v"(A3)
    : "memory");
}

// H [64,1024] bf16 (coherent) x Wslice^T (regs) -> partials into red (LDS).
// wave wid owns K in [wid*128, +128). Two-stage reduce -> 4 partial sets.
__device__ __forceinline__ void gemm_phase(const unsigned short* H,
                                           const short8 (&bfr)[3][4],
                                           float* red, int lane, int wid)
{
  const int l15 = lane & 15, q = lane >> 4;
  float4v acc[4][3];
#pragma unroll
  for (int mt=0; mt<4; ++mt)
#pragma unroll
    for (int nt=0; nt<3; ++nt) acc[mt][nt] = (float4v){0.f,0.f,0.f,0.f};

  short8 f[4][4];
  load_a16(H + (size_t)l15*NHID + wid*128 + q*8, f);
#pragma unroll
  for (int kt=0; kt<4; ++kt){
#pragma unroll
    for (int nt=0; nt<3; ++nt){
      acc[0][nt] = __builtin_amdgcn_mfma_f32_16x16x32_bf16(f[0][kt], bfr[nt][kt], acc[0][nt],0,0,0);
      acc[1][nt] = __builtin_amdgcn_mfma_f32_16x16x32_bf16(f[1][kt], bfr[nt][kt], acc[1][nt],0,0,0);
      acc[2][nt] = __builtin_amdgcn_mfma_f32_16x16x32_bf16(f[2][kt], bfr[nt][kt], acc[2][nt],0,0,0);
      acc[3][nt] = __builtin_amdgcn_mfma_f32_16x16x32_bf16(f[3][kt], bfr[nt][kt], acc[3][nt],0,0,0);
    }
  }
  if (wid >= 4){
#pragma unroll
    for (int mt=0; mt<4; ++mt)
#pragma unroll
      for (int nt=0; nt<3; ++nt){
        int n = nt*16 + l15, row = mt*16 + q*4;
        *(float4v*)(red + ((wid-4)*48 + n)*RS + row) = acc[mt][nt];
      }
  }
  __syncthreads();
  if (wid < 4){
#pragma unroll
    for (int mt=0; mt<4; ++mt)
#pragma unroll
      for (int nt=0; nt<3; ++nt){
        int n = nt*16 + l15, row = mt*16 + q*4;
        float4v* p = (float4v*)(red + (wid*48 + n)*RS + row);
        float4v v = *p;
        *p = v + acc[mt][nt];
      }
  }
  __syncthreads();
}

__device__ __forceinline__ void load_bfrags(const float* W, const int* rowbase,
                                            short8 (&bfr)[3][4], int lane, int wid)
{
  const int l15 = lane & 15, q = lane >> 4;
#pragma unroll
  for (int nt=0; nt<3; ++nt){
    const float* wp0 = W + (size_t)(rowbase[nt] + l15)*NHID + wid*128 + q*8;
#pragma unroll
    for (int kt=0; kt<4; ++kt){
      const float* wp = wp0 + kt*32;
      short8 fr;
#pragma unroll
      for (int j=0;j<8;++j) fr[j] = (short)f2bf(wp[j]);
      bfr[nt][kt] = fr;
    }
  }
}

__global__ __launch_bounds__(NTHR, 2) void mgru_fused(
    const int*   __restrict__ x,    const float* __restrict__ h0,
    const float* __restrict__ emb,
    const float* __restrict__ Wih0, const float* __restrict__ Whh0,
    const float* __restrict__ bih0, const float* __restrict__ bhh0,
    const float* __restrict__ Wih1, const float* __restrict__ Whh1,
    const float* __restrict__ bih1, const float* __restrict__ bhh1,
    const float* __restrict__ gamma, const float* __restrict__ beta,
    const float* __restrict__ Wout, const float* __restrict__ bout,
    float* __restrict__ out, char* ws)
{
  __shared__ __align__(16) char smem[LDS_BYTES];
  float* red = (float*)smem;

  unsigned* c0  = (unsigned*)(ws + OFF_C0);
  unsigned* c2  = (unsigned*)(ws + OFF_C2);
  unsigned* d2  = (unsigned*)(ws + OFF_D2);
  unsigned* fin = (unsigned*)(ws + OFF_FIN);
  unsigned short* y0ring = (unsigned short*)(ws + OFF_Y0);
  unsigned short* h1ring = (unsigned short*)(ws + OFF_H1);
  float*          T0     = (float*)(ws + OFF_T0);
  float*          stats  = (float*)(ws + OFF_ST);
  unsigned short* y1     = (unsigned short*)(ws + OFF_Y1);

  const int tid  = threadIdx.x;
  const int lane = tid & 63;
  const int wid  = tid >> 6;
  const int wg   = blockIdx.x;
  const int role = (wg < 64) ? 0 : 2;
  const int sub  = (role==0) ? wg : wg-64;

  const int ch0 = sub*16;
  const int cg  = tid >> 6;       // gate threads: tid<128 -> cg in {0,1}
  const int gb  = tid & 63;       // gate batch
  int rowbase[3] = {ch0, NHID + ch0, 2*NHID + ch0};

  if (role == 0){
    // ================= layer-0 recurrence =================
    short8 bfr[3][4];
    float hprev[8] = {0,0,0,0,0,0,0,0};
    float br[8], bz[8], bn[8];
    if (tid < 128){
      short8 pk;
#pragma unroll
      for (int j=0;j<8;++j){
        int c = ch0 + cg*8 + j;
        hprev[j] = h0[(size_t)gb*NHID + c];
        br[j] = bhh0[c]; bz[j] = bhh0[NHID + c]; bn[j] = bhh0[2*NHID + c];
        pk[j] = (short)f2bf(hprev[j]);
      }
      stc16_drain(y0ring + (size_t)NB*NHID + (size_t)gb*NHID + ch0 + cg*8, pk);
    }
    __syncthreads();
    if (tid == 0) sig(c0);                 // c0[0]: h0 slice visible

    // T0 slice: 31 x 48 dot products (WG-private, plain cached)
    for (int e = tid; e < NVOC*48; e += NTHR){
      int v = e / 48, n = e - v*48;
      int g = (n<16) ? (ch0+n) : (n<32 ? (NHID+ch0+n-16) : (2*NHID+ch0+n-32));
      const float4v* e4 = (const float4v*)(emb  + (size_t)v*NHID);
      const float4v* w4 = (const float4v*)(Wih0 + (size_t)g*NHID);
      float acc = 0.f;
      for (int k=0;k<NHID/4;++k){
        float4v a = e4[k], bb = w4[k];
        acc += a[0]*bb[0] + a[1]*bb[1] + a[2]*bb[2] + a[3]*bb[3];
      }
      T0[(size_t)v*3*NHID + g] = acc + bih0[g];
    }
    load_bfrags(Whh0, rowbase, bfr, lane, wid);
    __syncthreads();                       // T0 visible to whole WG

    for (int t = 0; t < NSEQ; ++t){
      if (tid == 0){
        waitc(c0 + (size_t)t*16, 64);                    // y0(t-1) ready (or init)
        if (t >= 2) waitc(d2 + (size_t)(t-2)*16, 64);    // WAR: role2 consumed y0(t-2)
      }
      __syncthreads();
      gemm_phase(y0ring + (size_t)((t+1)&1)*NB*NHID, bfr, red, lane, wid);
      if (tid < 128){
        int tok = x[(size_t)gb*NSEQ + t];
        const float* tr = T0 + (size_t)tok*3*NHID + ch0 + cg*8;
        short8 pk;
#pragma unroll
        for (int j=0;j<8;++j){
          float hr = br[j], hz = bz[j], hn = bn[j];
#pragma unroll
          for (int w=0;w<4;++w){
            hr += red[(w*48 +      cg*8 + j)*RS + gb];
            hz += red[(w*48 + 16 + cg*8 + j)*RS + gb];
            hn += red[(w*48 + 32 + cg*8 + j)*RS + gb];
          }
          float r = sigm(tr[j] + hr);
          float z = sigm(tr[NHID + j] + hz);
          float n = tanh_f(tr[2*NHID + j] + r*hn);
          float hnv = (1.f - z)*n + z*hprev[j];
          hprev[j] = hnv;
          pk[j] = (short)f2bf(hnv);
        }
        stc16_drain(y0ring + (size_t)(t&1)*NB*NHID + (size_t)gb*NHID + ch0 + cg*8, pk);
      }
      __syncthreads();
      if (tid == 0) sig(c0 + (size_t)(t+1)*16);
    }

  } else {
    // ================= layer-1 recurrence + xg + BN stats =================
    // Both weight fragment sets persistent in VGPRs (96 regs) — no global blob.
    short8 bfrH[3][4], wf[3][4];
    load_bfrags(Whh1, rowbase, bfrH, lane, wid);
    load_bfrags(Wih1, rowbase, wf,   lane, wid);

    float hprev[8] = {0,0,0,0,0,0,0,0};
    float s1[8] = {0,0,0,0,0,0,0,0}, s2[8] = {0,0,0,0,0,0,0,0};
    if (tid < 128){
      short8 pk;
#pragma unroll
      for (int j=0;j<8;++j){
        hprev[j] = h0[(size_t)NB*NHID + (size_t)gb*NHID + ch0 + cg*8 + j];
        pk[j] = (short)f2bf(hprev[j]);
      }
      stc16_drain(h1ring + (size_t)NB*NHID + (size_t)gb*NHID + ch0 + cg*8, pk);
    }
    __syncthreads();
    if (tid == 0) sig(c2);                  // c2[0]

    float* hp = (float*)(smem + LDS_HP_OFF) + (size_t)tid*25;

    for (int t = 0; t < NSEQ; ++t){
      if (tid == 0) waitc(c2 + (size_t)t*16, 64);   // h1(t-1) fully written
      __syncthreads();
      // gemmA: h-side gates from h1(t-1)
      gemm_phase(h1ring + (size_t)((t+1)&1)*NB*NHID, bfrH, red, lane, wid);
      if (tid < 128){
#pragma unroll
        for (int j=0;j<8;++j){
          int c = ch0 + cg*8 + j;
          float hr = bhh1[c], hz = bhh1[NHID + c], hn = bhh1[2*NHID + c];
#pragma unroll
          for (int w=0;w<4;++w){
            hr += red[(w*48 +      cg*8 + j)*RS + gb];
            hz += red[(w*48 + 16 + cg*8 + j)*RS + gb];
            hn += red[(w*48 + 32 + cg*8 + j)*RS + gb];
          }
          hp[j] = hr; hp[8+j] = hz; hp[16+j] = hn;
        }
      }
      if (tid == 0) waitc(c0 + (size_t)(t+1)*16, 64);   // y0(t) ready
      __syncthreads();                       // orders hp writes + red reuse
      // gemmB: x-side gates from y0(t)
      gemm_phase(y0ring + (size_t)(t&1)*NB*NHID, wf, red, lane, wid);
      if (tid == 0) sig(d2 + (size_t)t*16);  // y0(t) consumed
      if (tid < 128){
        short8 pk;
#pragma unroll
        for (int j=0;j<8;++j){
          int c = ch0 + cg*8 + j;
          float xr = bih1[c], xz = bih1[NHID + c], xn = bih1[2*NHID + c];
#pragma unroll
          for (int w=0;w<4;++w){
            xr += red[(w*48 +      cg*8 + j)*RS + gb];
            xz += red[(w*48 + 16 + cg*8 + j)*RS + gb];
            xn += red[(w*48 + 32 + cg*8 + j)*RS + gb];
          }
          float r = sigm(xr + hp[j]);
          float z = sigm(xz + hp[8+j]);
          float n = tanh_f(xn + r*hp[16+j]);
          float hnv = (1.f - z)*n + z*hprev[j];
          hprev[j] = hnv;
          unsigned short hb = f2bf(hnv);
          pk[j] = (short)hb;
          float hq = bf2f(hb);               // BN stats from stored bf16
          s1[j] += hq; s2[j] += hq*hq;
        }
        *(short8*)(y1 + (size_t)t*NB*NHID + (size_t)gb*NHID + ch0 + cg*8) = pk;  // plain
        stc16_drain(h1ring + (size_t)(t&1)*NB*NHID + (size_t)gb*NHID + ch0 + cg*8, pk);
      }
      __syncthreads();
      if (tid == 0) sig(c2 + (size_t)(t+1)*16);
    }

    // BN stats: reduce per channel over 64 batches (plain stores; fenced at fin)
    float* sb = (float*)smem;
    __syncthreads();
    if (tid < 128){
#pragma unroll
      for (int j=0;j<8;++j) sb[(cg*8 + j)*64 + gb] = s1[j];
    }
    __syncthreads();
    if (tid < 16){
      float a = 0.f;
      for (int i=0;i<64;++i) a += sb[tid*64 + i];
      stats[ch0 + tid] = a;
    }
    __syncthreads();
    if (tid < 128){
#pragma unroll
      for (int j=0;j<8;++j) sb[(cg*8 + j)*64 + gb] = s2[j];
    }
    __syncthreads();
    if (tid < 16){
      float a = 0.f;
      for (int i=0;i<64;++i) a += sb[tid*64 + i];
      stats[NHID + ch0 + tid] = a;
    }
  }

  // ======== fin barrier with ONE wbL2/inv fence pair per WG ========
  __syncthreads();
  if (tid == 0){
    __threadfence();          // release: writeback dirty L2 (y1, stats)
    sig(fin);
    waitc(fin, NBLK);
    __threadfence();          // acquire: invalidate stale L2 lines
  }
  __syncthreads();

  // ================= epilogue: fold BN into Wout, GEMM -> out =================
  const float inv_n = 1.f/32768.f;
  const int l15 = lane & 15, q = lane >> 4;

  float* bpart    = (float*)smem;
  float* bprime_l = (float*)(smem + 2048);
  {
    int v = tid >> 4, k0 = tid & 15;
    float partial = 0.f;
    if (v < NVOC){
      for (int k = k0; k < NHID; k += 16){
        float mu  = stats[k]*inv_n;
        float var = stats[NHID+k]*inv_n - mu*mu;
        float sc  = gamma[k]*rsqrtf(var + EPSV);
        partial += (beta[k] - mu*sc) * Wout[(size_t)v*NHID + k];
      }
    }
    bpart[tid] = partial;
  }
  __syncthreads();
  if (tid < 32){
    float bpv = 0.f;
    for (int j=0;j<16;++j) bpv += bpart[tid*16 + j];
    bprime_l[tid] = (tid < NVOC) ? (bpv + bout[tid]) : 0.f;
  }
  __syncthreads();
  float bp_a = bprime_l[l15];
  float bp_b = (l15 < 15) ? bprime_l[16 + l15] : 0.f;
  __syncthreads();

  unsigned short* wsc = (unsigned short*)smem;   // [31][1032] bf16
  for (int e = tid; e < NVOC*1032; e += NTHR){
    int v = e / 1032, k = e - v*1032;
    float val = 0.f;
    if (k < NHID){
      float mu  = stats[k]*inv_n;
      float var = stats[NHID+k]*inv_n - mu*mu;
      float sc  = gamma[k]*rsqrtf(var + EPSV);
      val = Wout[(size_t)v*NHID + k] * sc;
    }
    wsc[e] = f2bf(val);
  }
  __syncthreads();

  int wglob = wg*8 + wid;       // 0..1023, 512 jobs on even waves
  if ((wglob & 1) == 0){
    int J = wglob >> 1;         // 0..511, each = 64 rows of the 32768-row output
    float4v acc[4][2];
#pragma unroll
    for (int mt=0;mt<4;++mt){ acc[mt][0] = (float4v){0,0,0,0}; acc[mt][1] = (float4v){0,0,0,0}; }
    const unsigned short* abase = y1 + (size_t)(J*64 + l15)*NHID + q*8;
    const short8 zero8 = (short8){0,0,0,0,0,0,0,0};
#pragma unroll 4
    for (int kt=0; kt<32; ++kt){
      short8 bv0 = *(const short8*)(wsc + (size_t)l15*1032 + kt*32 + q*8);
      short8 bv1 = (l15 < 15) ? *(const short8*)(wsc + (size_t)(16+l15)*1032 + kt*32 + q*8) : zero8;
      short8 a0 = *(const short8*)(abase + (size_t)kt*32);
      short8 a1 = *(const short8*)(abase + 16*NHID + (size_t)kt*32);
      short8 a2 = *(const short8*)(abase + 32*NHID + (size_t)kt*32);
      short8 a3 = *(const short8*)(abase + 48*NHID + (size_t)kt*32);
      acc[0][0] = __builtin_amdgcn_mfma_f32_16x16x32_bf16(a0, bv0, acc[0][0],0,0,0);
      acc[1][0] = __builtin_amdgcn_mfma_f32_16x16x32_bf16(a1, bv0, acc[1][0],0,0,0);
      acc[2][0] = __builtin_amdgcn_mfma_f32_16x16x32_bf16(a2, bv0, acc[2][0],0,0,0);
      acc[3][0] = __builtin_amdgcn_mfma_f32_16x16x32_bf16(a3, bv0, acc[3][0],0,0,0);
      acc[0][1] = __builtin_amdgcn_mfma_f32_16x16x32_bf16(a0, bv1, acc[0][1],0,0,0);
      acc[1][1] = __builtin_amdgcn_mfma_f32_16x16x32_bf16(a1, bv1, acc[1][1],0,0,0);
      acc[2][1] = __builtin_amdgcn_mfma_f32_16x16x32_bf16(a2, bv1, acc[2][1],0,0,0);
      acc[3][1] = __builtin_amdgcn_mfma_f32_16x16x32_bf16(a3, bv1, acc[3][1],0,0,0);
    }
#pragma unroll
    for (int mt=0;mt<4;++mt){
#pragma unroll
      for (int nt=0;nt<2;++nt){
        int v = nt*16 + l15;
        if (v < NVOC){
          float bpv = (nt==0) ? bp_a : bp_b;
          int r0 = J*64 + mt*16 + q*4;
#pragma unroll
          for (int i2=0;i2<4;++i2){
            int r = r0 + i2;
            int b = r & 63, tt = r >> 6;
            out[(size_t)(b*NSEQ + tt)*NVOC + v] = acc[mt][nt][i2] + bpv;
          }
        }
      }
    }
  }
}

extern "C" void kernel_launch(void* const* d_in, const int* in_sizes, int n_in,
                              void* d_out, int out_size, void* d_ws, size_t ws_size,
                              hipStream_t stream) {
  (void)in_sizes; (void)n_in; (void)out_size; (void)ws_size;
  hipMemsetAsync(d_ws, 0, CNT_BYTES, stream);   // zero all sync counters
  mgru_fused<<<dim3(NBLK), dim3(NTHR), 0, stream>>>(
      (const int*)d_in[0],  (const float*)d_in[1],  (const float*)d_in[2],
      (const float*)d_in[3], (const float*)d_in[4], (const float*)d_in[5],
      (const float*)d_in[6], (const float*)d_in[7], (const float*)d_in[8],
      (const float*)d_in[9], (const float*)d_in[10], (const float*)d_in[11],
      (const float*)d_in[12], (const float*)d_in[13], (const float*)d_in[14],
      (float*)d_out, (char*)d_ws);
}

// Round 5
// 7221.899 us; speedup vs baseline: 1.2749x; 1.2749x over previous
//
#include <hip/hip_runtime.h>
#include <cstddef>
#include <stdint.h>

// ---------------- problem constants ----------------
#define NHID 1024
#define NVOC 31
#define NB   64
#define NSEQ 512
#define NBLK 128     // 64 role0 (layer0) + 64 role2 (layer1 + xg)
#define NTHR 512     // 8 waves
#define EPSV 1e-5f
#define RS   68      // LDS reduce stride: 68*4B=272, 16B-aligned rows

typedef __attribute__((ext_vector_type(8))) short short8;   // 8 x bf16
typedef __attribute__((ext_vector_type(4))) float float4v;

// ---------------- workspace layout (bytes) ----------------
// Per-WG monotonic flags (64B-strided: one cacheline each, stores never RMW).
// Value semantics: f = k+2 means the WG finished step k; f = 1 means init done.
#define OFF_F0  0               // 64 flags: role0 (y0 producer)
#define OFF_F2  4096            // 64 flags: role2 (h1 producer / y0 consumer)
#define OFF_FIN 8192            // one counter (single end-of-kernel RMW per WG)
#define CNT_BYTES 8256
#define OFF_Y0  8448            // y0 ring: 4 x [64][1024] bf16 (512KB)
#define OFF_H1  532736          // h1 ring: 2 x [64][1024] bf16 (256KB)
#define OFF_T0  794880          // T0: [31][3072] f32 (role0-WG-private)
#define OFF_ST  1175808         // stats: [2][1024] f32
#define OFF_Y1  1184000         // y1: [512][64][1024] bf16 (64MB) -> total ~68.3MB

// LDS: red = 192 rows x RS floats = 52224B; hpart = 128 thr x 25 floats = 12800B
#define LDS_HP_OFF 52224
#define LDS_BYTES  65024

__device__ __forceinline__ unsigned short f2bf(float f){
  unsigned u = __builtin_bit_cast(unsigned, f);
  u += 0x7fffu + ((u >> 16) & 1u);               // RNE
  return (unsigned short)(u >> 16);
}
__device__ __forceinline__ float bf2f(unsigned short h){
  unsigned u = ((unsigned)h) << 16;
  return __builtin_bit_cast(float, u);
}
__device__ __forceinline__ float sigm(float x){ return 1.f/(1.f + __expf(-x)); }
__device__ __forceinline__ float tanh_f(float x){ return 1.f - 2.f/(__expf(2.f*x) + 1.f); }

// ---- flag-based sync: plain coherent stores + wave-parallel polling ----
__device__ __forceinline__ void setflag(unsigned* f, unsigned v){
  __hip_atomic_store(f, v, __ATOMIC_RELAXED, __HIP_MEMORY_SCOPE_AGENT);
}
// wave-wide: lane i polls flags[i]; exits when ALL 64 flags >= target
__device__ __forceinline__ void wait1(const unsigned* flags, int target, int lane){
  const unsigned* p = flags + (size_t)lane*16;
  for(;;){
    int v = (int)__hip_atomic_load(p, __ATOMIC_RELAXED, __HIP_MEMORY_SCOPE_AGENT);
    if (__all(v >= target)) break;
    __builtin_amdgcn_s_sleep(1);
  }
}
__device__ __forceinline__ void wait2(const unsigned* fA, int ta,
                                      const unsigned* fB, int tb, int lane){
  const unsigned* pa = fA + (size_t)lane*16;
  const unsigned* pb = fB + (size_t)lane*16;
  for(;;){
    int va = (int)__hip_atomic_load(pa, __ATOMIC_RELAXED, __HIP_MEMORY_SCOPE_AGENT);
    int vb = (int)__hip_atomic_load(pb, __ATOMIC_RELAXED, __HIP_MEMORY_SCOPE_AGENT);
    if (__all((va >= ta) && (vb >= tb))) break;
    __builtin_amdgcn_s_sleep(1);
  }
}
__device__ __forceinline__ void sig(unsigned* c){
  __hip_atomic_fetch_add(c, 1u, __ATOMIC_RELAXED, __HIP_MEMORY_SCOPE_AGENT);
}
__device__ __forceinline__ void waitc(unsigned* c, unsigned v){
  while (__hip_atomic_load(c, __ATOMIC_RELAXED, __HIP_MEMORY_SCOPE_AGENT) < v)
    __builtin_amdgcn_s_sleep(1);
}

// 16B agent-coherent store + drain
__device__ __forceinline__ void stc16_drain(void* p, short8 v){
  asm volatile("global_store_dwordx4 %0, %1, off sc1\n\t"
               "s_waitcnt vmcnt(0)"
               :: "v"((unsigned long long)(uintptr_t)p), "v"(v) : "memory");
}

// Load 16 A-fragments of H via 16B agent-coherent loads (early-clobber outputs).
__device__ __forceinline__ void load_a16(const unsigned short* base, short8 (&f)[4][4]){
  unsigned long long A0 = (unsigned long long)(uintptr_t)base;
  unsigned long long A1 = A0 + (unsigned long long)(16*NHID*2);
  unsigned long long A2 = A0 + (unsigned long long)(32*NHID*2);
  unsigned long long A3 = A0 + (unsigned long long)(48*NHID*2);
  asm volatile(
    "global_load_dwordx4 %0, %16, off sc1\n\t"
    "global_load_dwordx4 %1, %16, off offset:64 sc1\n\t"
    "global_load_dwordx4 %2, %16, off offset:128 sc1\n\t"
    "global_load_dwordx4 %3, %16, off offset:192 sc1\n\t"
    "global_load_dwordx4 %4, %17, off sc1\n\t"
    "global_load_dwordx4 %5, %17, off offset:64 sc1\n\t"
    "global_load_dwordx4 %6, %17, off offset:128 sc1\n\t"
    "global_load_dwordx4 %7, %17, off offset:192 sc1\n\t"
    "global_load_dwordx4 %8, %18, off sc1\n\t"
    "global_load_dwordx4 %9, %18, off offset:64 sc1\n\t"
    "global_load_dwordx4 %10, %18, off offset:128 sc1\n\t"
    "global_load_dwordx4 %11, %18, off offset:192 sc1\n\t"
    "global_load_dwordx4 %12, %19, off sc1\n\t"
    "global_load_dwordx4 %13, %19, off offset:64 sc1\n\t"
    "global_load_dwordx4 %14, %19, off offset:128 sc1\n\t"
    "global_load_dwordx4 %15, %19, off offset:192 sc1\n\t"
    "s_waitcnt vmcnt(0)"
    : "=&v"(f[0][0]), "=&v"(f[0][1]), "=&v"(f[0][2]), "=&v"(f[0][3]),
      "=&v"(f[1][0]), "=&v"(f[1][1]), "=&v"(f[1][2]), "=&v"(f[1][3]),
      "=&v"(f[2][0]), "=&v"(f[2][1]), "=&v"(f[2][2]), "=&v"(f[2][3]),
      "=&v"(f[3][0]), "=&v"(f[3][1]), "=&v"(f[3][2]), "=&v"(f[3][3])
    : "v"(A0), "v"(A1), "v"(A2), "v"(A3)
    : "memory");
}

// H [64,1024] bf16 (coherent) x Wslice^T (regs) -> partials into red (LDS).
__device__ __forceinline__ void gemm_phase(const unsigned short* H,
                                           const short8 (&bfr)[3][4],
                                           float* red, int lane, int wid)
{
  const int l15 = lane & 15, q = lane >> 4;
  float4v acc[4][3];
#pragma unroll
  for (int mt=0; mt<4; ++mt)
#pragma unroll
    for (int nt=0; nt<3; ++nt) acc[mt][nt] = (float4v){0.f,0.f,0.f,0.f};

  short8 f[4][4];
  load_a16(H + (size_t)l15*NHID + wid*128 + q*8, f);
#pragma unroll
  for (int kt=0; kt<4; ++kt){
#pragma unroll
    for (int nt=0; nt<3; ++nt){
      acc[0][nt] = __builtin_amdgcn_mfma_f32_16x16x32_bf16(f[0][kt], bfr[nt][kt], acc[0][nt],0,0,0);
      acc[1][nt] = __builtin_amdgcn_mfma_f32_16x16x32_bf16(f[1][kt], bfr[nt][kt], acc[1][nt],0,0,0);
      acc[2][nt] = __builtin_amdgcn_mfma_f32_16x16x32_bf16(f[2][kt], bfr[nt][kt], acc[2][nt],0,0,0);
      acc[3][nt] = __builtin_amdgcn_mfma_f32_16x16x32_bf16(f[3][kt], bfr[nt][kt], acc[3][nt],0,0,0);
    }
  }
  if (wid >= 4){
#pragma unroll
    for (int mt=0; mt<4; ++mt)
#pragma unroll
      for (int nt=0; nt<3; ++nt){
        int n = nt*16 + l15, row = mt*16 + q*4;
        *(float4v*)(red + ((wid-4)*48 + n)*RS + row) = acc[mt][nt];
      }
  }
  __syncthreads();
  if (wid < 4){
#pragma unroll
    for (int mt=0; mt<4; ++mt)
#pragma unroll
      for (int nt=0; nt<3; ++nt){
        int n = nt*16 + l15, row = mt*16 + q*4;
        float4v* p = (float4v*)(red + (wid*48 + n)*RS + row);
        float4v v = *p;
        *p = v + acc[mt][nt];
      }
  }
  __syncthreads();
}

__device__ __forceinline__ void load_bfrags(const float* W, const int* rowbase,
                                            short8 (&bfr)[3][4], int lane, int wid)
{
  const int l15 = lane & 15, q = lane >> 4;
#pragma unroll
  for (int nt=0; nt<3; ++nt){
    const float* wp0 = W + (size_t)(rowbase[nt] + l15)*NHID + wid*128 + q*8;
#pragma unroll
    for (int kt=0; kt<4; ++kt){
      const float* wp = wp0 + kt*32;
      short8 fr;
#pragma unroll
      for (int j=0;j<8;++j) fr[j] = (short)f2bf(wp[j]);
      bfr[nt][kt] = fr;
    }
  }
}

__global__ __launch_bounds__(NTHR, 2) void mgru_fused(
    const int*   __restrict__ x,    const float* __restrict__ h0,
    const float* __restrict__ emb,
    const float* __restrict__ Wih0, const float* __restrict__ Whh0,
    const float* __restrict__ bih0, const float* __restrict__ bhh0,
    const float* __restrict__ Wih1, const float* __restrict__ Whh1,
    const float* __restrict__ bih1, const float* __restrict__ bhh1,
    const float* __restrict__ gamma, const float* __restrict__ beta,
    const float* __restrict__ Wout, const float* __restrict__ bout,
    float* __restrict__ out, char* ws)
{
  __shared__ __align__(16) char smem[LDS_BYTES];
  float* red = (float*)smem;

  unsigned* f0  = (unsigned*)(ws + OFF_F0);
  unsigned* f2  = (unsigned*)(ws + OFF_F2);
  unsigned* fin = (unsigned*)(ws + OFF_FIN);
  unsigned short* y0ring = (unsigned short*)(ws + OFF_Y0);   // 4 slots
  unsigned short* h1ring = (unsigned short*)(ws + OFF_H1);   // 2 slots
  float*          T0     = (float*)(ws + OFF_T0);
  float*          stats  = (float*)(ws + OFF_ST);
  unsigned short* y1     = (unsigned short*)(ws + OFF_Y1);

  const int tid  = threadIdx.x;
  const int lane = tid & 63;
  const int wid  = tid >> 6;
  const int wg   = blockIdx.x;
  const int role = (wg < 64) ? 0 : 2;
  const int sub  = (role==0) ? wg : wg-64;

  const int ch0 = sub*16;
  const int cg  = tid >> 6;       // gate threads: tid<128 -> cg in {0,1}
  const int gb  = tid & 63;       // gate batch
  int rowbase[3] = {ch0, NHID + ch0, 2*NHID + ch0};

  if (role == 0){
    // ================= layer-0 recurrence =================
    short8 bfr[3][4];
    float hprev[8] = {0,0,0,0,0,0,0,0};
    float br[8], bz[8], bn[8];
    if (tid < 128){
      short8 pk;
#pragma unroll
      for (int j=0;j<8;++j){
        int c = ch0 + cg*8 + j;
        hprev[j] = h0[(size_t)gb*NHID + c];
        br[j] = bhh0[c]; bz[j] = bhh0[NHID + c]; bn[j] = bhh0[2*NHID + c];
        pk[j] = (short)f2bf(hprev[j]);
      }
      // y0(-1) lives in slot (0-1)&3 = 3
      stc16_drain(y0ring + (size_t)3*NB*NHID + (size_t)gb*NHID + ch0 + cg*8, pk);
    }
    __syncthreads();
    if (tid == 0) setflag(f0 + (size_t)wg*16, 1u);   // init done

    // T0 slice: 31 x 48 dot products (WG-private, plain cached)
    for (int e = tid; e < NVOC*48; e += NTHR){
      int v = e / 48, n = e - v*48;
      int g = (n<16) ? (ch0+n) : (n<32 ? (NHID+ch0+n-16) : (2*NHID+ch0+n-32));
      const float4v* e4 = (const float4v*)(emb  + (size_t)v*NHID);
      const float4v* w4 = (const float4v*)(Wih0 + (size_t)g*NHID);
      float acc = 0.f;
      for (int k=0;k<NHID/4;++k){
        float4v a = e4[k], bb = w4[k];
        acc += a[0]*bb[0] + a[1]*bb[1] + a[2]*bb[2] + a[3]*bb[3];
      }
      T0[(size_t)v*3*NHID + g] = acc + bih0[g];
    }
    load_bfrags(Whh0, rowbase, bfr, lane, wid);
    __syncthreads();                       // T0 visible to whole WG

    for (int t = 0; t < NSEQ; ++t){
      // need y0(t-1): f0 >= t+1;  WAR on slot t&3 (=y0(t-4)): role2 done t-4: f2 >= t-2
      if (wid == 0) wait2(f0, t+1, f2, t-2, lane);
      __syncthreads();
      gemm_phase(y0ring + (size_t)((t+3)&3)*NB*NHID, bfr, red, lane, wid);
      if (tid < 128){
        int tok = x[(size_t)gb*NSEQ + t];
        const float* tr = T0 + (size_t)tok*3*NHID + ch0 + cg*8;
        short8 pk;
#pragma unroll
        for (int j=0;j<8;++j){
          float hr = br[j], hz = bz[j], hn = bn[j];
#pragma unroll
          for (int w=0;w<4;++w){
            hr += red[(w*48 +      cg*8 + j)*RS + gb];
            hz += red[(w*48 + 16 + cg*8 + j)*RS + gb];
            hn += red[(w*48 + 32 + cg*8 + j)*RS + gb];
          }
          float r = sigm(tr[j] + hr);
          float z = sigm(tr[NHID + j] + hz);
          float n = tanh_f(tr[2*NHID + j] + r*hn);
          float hnv = (1.f - z)*n + z*hprev[j];
          hprev[j] = hnv;
          pk[j] = (short)f2bf(hnv);
        }
        stc16_drain(y0ring + (size_t)(t&3)*NB*NHID + (size_t)gb*NHID + ch0 + cg*8, pk);
      }
      __syncthreads();
      if (tid == 0) setflag(f0 + (size_t)wg*16, (unsigned)(t+2));
    }

  } else {
    // ================= layer-1 recurrence + xg + BN stats =================
    short8 bfrH[3][4], wf[3][4];
    load_bfrags(Whh1, rowbase, bfrH, lane, wid);
    load_bfrags(Wih1, rowbase, wf,   lane, wid);

    float hprev[8] = {0,0,0,0,0,0,0,0};
    float s1[8] = {0,0,0,0,0,0,0,0}, s2[8] = {0,0,0,0,0,0,0,0};
    if (tid < 128){
      short8 pk;
#pragma unroll
      for (int j=0;j<8;++j){
        hprev[j] = h0[(size_t)NB*NHID + (size_t)gb*NHID + ch0 + cg*8 + j];
        pk[j] = (short)f2bf(hprev[j]);
      }
      // h1(-1) lives in slot (0-1)&1 = 1
      stc16_drain(h1ring + (size_t)NB*NHID + (size_t)gb*NHID + ch0 + cg*8, pk);
    }
    __syncthreads();
    if (tid == 0) setflag(f2 + (size_t)sub*16, 1u);   // init done

    float* hp = (float*)(smem + LDS_HP_OFF) + (size_t)tid*25;

    for (int t = 0; t < NSEQ; ++t){
      if (wid == 0) wait1(f2, t+1, lane);   // h1(t-1) fully written (all role2 WGs)
      __syncthreads();
      // gemmA: h-side gates from h1(t-1)
      gemm_phase(h1ring + (size_t)((t+1)&1)*NB*NHID, bfrH, red, lane, wid);
      if (tid < 128){
#pragma unroll
        for (int j=0;j<8;++j){
          int c = ch0 + cg*8 + j;
          float hr = bhh1[c], hz = bhh1[NHID + c], hn = bhh1[2*NHID + c];
#pragma unroll
          for (int w=0;w<4;++w){
            hr += red[(w*48 +      cg*8 + j)*RS + gb];
            hz += red[(w*48 + 16 + cg*8 + j)*RS + gb];
            hn += red[(w*48 + 32 + cg*8 + j)*RS + gb];
          }
          hp[j] = hr; hp[8+j] = hz; hp[16+j] = hn;
        }
      }
      if (wid == 0) wait1(f0, t+2, lane);   // y0(t) ready (all role0 WGs)
      __syncthreads();                       // orders hp writes + red reuse
      // gemmB: x-side gates from y0(t)
      gemm_phase(y0ring + (size_t)(t&3)*NB*NHID, wf, red, lane, wid);
      if (tid < 128){
        short8 pk;
#pragma unroll
        for (int j=0;j<8;++j){
          int c = ch0 + cg*8 + j;
          float xr = bih1[c], xz = bih1[NHID + c], xn = bih1[2*NHID + c];
#pragma unroll
          for (int w=0;w<4;++w){
            xr += red[(w*48 +      cg*8 + j)*RS + gb];
            xz += red[(w*48 + 16 + cg*8 + j)*RS + gb];
            xn += red[(w*48 + 32 + cg*8 + j)*RS + gb];
          }
          float r = sigm(xr + hp[j]);
          float z = sigm(xz + hp[8+j]);
          float n = tanh_f(xn + r*hp[16+j]);
          float hnv = (1.f - z)*n + z*hprev[j];
          hprev[j] = hnv;
          unsigned short hb = f2bf(hnv);
          pk[j] = (short)hb;
          float hq = bf2f(hb);               // BN stats from stored bf16
          s1[j] += hq; s2[j] += hq*hq;
        }
        *(short8*)(y1 + (size_t)t*NB*NHID + (size_t)gb*NHID + ch0 + cg*8) = pk;  // plain
        stc16_drain(h1ring + (size_t)(t&1)*NB*NHID + (size_t)gb*NHID + ch0 + cg*8, pk);
      }
      __syncthreads();
      if (tid == 0) setflag(f2 + (size_t)sub*16, (unsigned)(t+2));
    }

    // BN stats: reduce per channel over 64 batches (plain stores; fenced at fin)
    float* sb = (float*)smem;
    __syncthreads();
    if (tid < 128){
#pragma unroll
      for (int j=0;j<8;++j) sb[(cg*8 + j)*64 + gb] = s1[j];
    }
    __syncthreads();
    if (tid < 16){
      float a = 0.f;
      for (int i=0;i<64;++i) a += sb[tid*64 + i];
      stats[ch0 + tid] = a;
    }
    __syncthreads();
    if (tid < 128){
#pragma unroll
      for (int j=0;j<8;++j) sb[(cg*8 + j)*64 + gb] = s2[j];
    }
    __syncthreads();
    if (tid < 16){
      float a = 0.f;
      for (int i=0;i<64;++i) a += sb[tid*64 + i];
      stats[NHID + ch0 + tid] = a;
    }
  }

  // ======== fin barrier with ONE wbL2/inv fence pair per WG ========
  __syncthreads();
  if (tid == 0){
    __threadfence();          // release: writeback dirty L2 (y1, stats)
    sig(fin);
    waitc(fin, NBLK);
    __threadfence();          // acquire: invalidate stale L2 lines
  }
  __syncthreads();

  // ================= epilogue: fold BN into Wout, GEMM -> out =================
  const float inv_n = 1.f/32768.f;
  const int l15 = lane & 15, q = lane >> 4;

  float* bpart    = (float*)smem;
  float* bprime_l = (float*)(smem + 2048);
  {
    int v = tid >> 4, k0 = tid & 15;
    float partial = 0.f;
    if (v < NVOC){
      for (int k = k0; k < NHID; k += 16){
        float mu  = stats[k]*inv_n;
        float var = stats[NHID+k]*inv_n - mu*mu;
        float sc  = gamma[k]*rsqrtf(var + EPSV);
        partial += (beta[k] - mu*sc) * Wout[(size_t)v*NHID + k];
      }
    }
    bpart[tid] = partial;
  }
  __syncthreads();
  if (tid < 32){
    float bpv = 0.f;
    for (int j=0;j<16;++j) bpv += bpart[tid*16 + j];
    bprime_l[tid] = (tid < NVOC) ? (bpv + bout[tid]) : 0.f;
  }
  __syncthreads();
  float bp_a = bprime_l[l15];
  float bp_b = (l15 < 15) ? bprime_l[16 + l15] : 0.f;
  __syncthreads();

  unsigned short* wsc = (unsigned short*)smem;   // [31][1032] bf16
  for (int e = tid; e < NVOC*1032; e += NTHR){
    int v = e / 1032, k = e - v*1032;
    float val = 0.f;
    if (k < NHID){
      float mu  = stats[k]*inv_n;
      float var = stats[NHID+k]*inv_n - mu*mu;
      float sc  = gamma[k]*rsqrtf(var + EPSV);
      val = Wout[(size_t)v*NHID + k] * sc;
    }
    wsc[e] = f2bf(val);
  }
  __syncthreads();

  int wglob = wg*8 + wid;       // 0..1023, 512 jobs on even waves
  if ((wglob & 1) == 0){
    int J = wglob >> 1;         // 0..511, each = 64 rows of the 32768-row output
    float4v acc[4][2];
#pragma unroll
    for (int mt=0;mt<4;++mt){ acc[mt][0] = (float4v){0,0,0,0}; acc[mt][1] = (float4v){0,0,0,0}; }
    const unsigned short* abase = y1 + (size_t)(J*64 + l15)*NHID + q*8;
    const short8 zero8 = (short8){0,0,0,0,0,0,0,0};
#pragma unroll 4
    for (int kt=0; kt<32; ++kt){
      short8 bv0 = *(const short8*)(wsc + (size_t)l15*1032 + kt*32 + q*8);
      short8 bv1 = (l15 < 15) ? *(const short8*)(wsc + (size_t)(16+l15)*1032 + kt*32 + q*8) : zero8;
      short8 a0 = *(const short8*)(abase + (size_t)kt*32);
      short8 a1 = *(const short8*)(abase + 16*NHID + (size_t)kt*32);
      short8 a2 = *(const short8*)(abase + 32*NHID + (size_t)kt*32);
      short8 a3 = *(const short8*)(abase + 48*NHID + (size_t)kt*32);
      acc[0][0] = __builtin_amdgcn_mfma_f32_16x16x32_bf16(a0, bv0, acc[0][0],0,0,0);
      acc[1][0] = __builtin_amdgcn_mfma_f32_16x16x32_bf16(a1, bv0, acc[1][0],0,0,0);
      acc[2][0] = __builtin_amdgcn_mfma_f32_16x16x32_bf16(a2, bv0, acc[2][0],0,0,0);
      acc[3][0] = __builtin_amdgcn_mfma_f32_16x16x32_bf16(a3, bv0, acc[3][0],0,0,0);
      acc[0][1] = __builtin_amdgcn_mfma_f32_16x16x32_bf16(a0, bv1, acc[0][1],0,0,0);
      acc[1][1] = __builtin_amdgcn_mfma_f32_16x16x32_bf16(a1, bv1, acc[1][1],0,0,0);
      acc[2][1] = __builtin_amdgcn_mfma_f32_16x16x32_bf16(a2, bv1, acc[2][1],0,0,0);
      acc[3][1] = __builtin_amdgcn_mfma_f32_16x16x32_bf16(a3, bv1, acc[3][1],0,0,0);
    }
#pragma unroll
    for (int mt=0;mt<4;++mt){
#pragma unroll
      for (int nt=0;nt<2;++nt){
        int v = nt*16 + l15;
        if (v < NVOC){
          float bpv = (nt==0) ? bp_a : bp_b;
          int r0 = J*64 + mt*16 + q*4;
#pragma unroll
          for (int i2=0;i2<4;++i2){
            int r = r0 + i2;
            int b = r & 63, tt = r >> 6;
            out[(size_t)(b*NSEQ + tt)*NVOC + v] = acc[mt][nt][i2] + bpv;
          }
        }
      }
    }
  }
}

extern "C" void kernel_launch(void* const* d_in, const int* in_sizes, int n_in,
                              void* d_out, int out_size, void* d_ws, size_t ws_size,
                              hipStream_t stream) {
  (void)in_sizes; (void)n_in; (void)out_size; (void)ws_size;
  hipMemsetAsync(d_ws, 0, CNT_BYTES, stream);   // zero flags + fin counter
  mgru_fused<<<dim3(NBLK), dim3(NTHR), 0, stream>>>(
      (const int*)d_in[0],  (const float*)d_in[1],  (const float*)d_in[2],
      (const float*)d_in[3], (const float*)d_in[4], (const float*)d_in[5],
      (const float*)d_in[6], (const float*)d_in[7], (const float*)d_in[8],
      (const float*)d_in[9], (const float*)d_in[10], (const float*)d_in[11],
      (const float*)d_in[12], (const float*)d_in[13], (const float*)d_in[14],
      (float*)d_out, (char*)d_ws);
}

// Round 6
// 6996.861 us; speedup vs baseline: 1.3160x; 1.0322x over previous
//
#include <hip/hip_runtime.h>
#include <cstddef>
#include <stdint.h>

// ---------------- problem constants ----------------
#define NHID 1024
#define NVOC 31
#define NB   64
#define NSEQ 512
#define NBLK 128     // 64 role0 (layer0) + 64 role2 (layer1 + xg)
#define NTHR 512     // 8 waves
#define EPSV 1e-5f
#define RS   68      // LDS reduce stride
#define SL   (NB*NHID)   // one h-state slot, elements (128KB as bf16)

typedef __attribute__((ext_vector_type(8))) short short8;   // 8 x bf16
typedef __attribute__((ext_vector_type(4))) float float4v;

// ---------------- common sync area ----------------
#define OFF_F0  0               // 64 flags, 64B-strided: role0 progress
#define OFF_F2  4096            // 64 flags: role2 progress
#define OFF_FIN 8192
#define CNT_BYTES 8256

// ---------------- RING layout (fallback, = R5) ----------------
#define R_OFF_Y0  8448          // y0 ring: 4 slots
#define R_OFF_H1  532736        // h1 ring: 2 slots
#define R_OFF_T0  794880
#define R_OFF_ST  1175808
#define R_OFF_Y1  1184000       // y1 history (64MB)

// ---------------- MONO layout (preferred) ----------------
// y0 history: 513 slots (slot t+1 = y0(t), slot 0 = y0(-1))
#define M_OFF_Y0  8448
#define M_OFF_Y1  (M_OFF_Y0 + 513ull*SL*2)         // 512 slots: y1(t) == h1(t)
#define M_OFF_H1I (M_OFF_Y1 + 512ull*SL*2)         // h1(-1), 1 slot
#define M_OFF_T0  (M_OFF_H1I + (unsigned long long)SL*2)
#define M_OFF_ST  (M_OFF_T0 + 31ull*3*NHID*4)
#define NEED_MONO (M_OFF_ST + 2ull*NHID*4)

// LDS: red = 192 rows x RS floats = 52224B; hpart = 128 thr x 25 floats
#define LDS_HP_OFF 52224
#define LDS_BYTES  65024

__device__ __forceinline__ unsigned short f2bf(float f){
  unsigned u = __builtin_bit_cast(unsigned, f);
  u += 0x7fffu + ((u >> 16) & 1u);               // RNE
  return (unsigned short)(u >> 16);
}
__device__ __forceinline__ float bf2f(unsigned short h){
  unsigned u = ((unsigned)h) << 16;
  return __builtin_bit_cast(float, u);
}
__device__ __forceinline__ float sigm(float x){ return 1.f/(1.f + __expf(-x)); }
__device__ __forceinline__ float tanh_f(float x){ return 1.f - 2.f/(__expf(2.f*x) + 1.f); }

// ---- flag sync: per-WG monotonic stores + wave-parallel polling ----
__device__ __forceinline__ void setflag(unsigned* f, unsigned v){
  __hip_atomic_store(f, v, __ATOMIC_RELAXED, __HIP_MEMORY_SCOPE_AGENT);
}
__device__ __forceinline__ void wait1(const unsigned* flags, int target, int lane){
  const unsigned* p = flags + (size_t)lane*16;
  for(;;){
    int v = (int)__hip_atomic_load(p, __ATOMIC_RELAXED, __HIP_MEMORY_SCOPE_AGENT);
    if (__all(v >= target)) break;
    __builtin_amdgcn_s_sleep(1);
  }
}
__device__ __forceinline__ void wait2(const unsigned* fA, int ta,
                                      const unsigned* fB, int tb, int lane){
  const unsigned* pa = fA + (size_t)lane*16;
  const unsigned* pb = fB + (size_t)lane*16;
  for(;;){
    int va = (int)__hip_atomic_load(pa, __ATOMIC_RELAXED, __HIP_MEMORY_SCOPE_AGENT);
    int vb = (int)__hip_atomic_load(pb, __ATOMIC_RELAXED, __HIP_MEMORY_SCOPE_AGENT);
    if (__all((va >= ta) && (vb >= tb))) break;
    __builtin_amdgcn_s_sleep(1);
  }
}
__device__ __forceinline__ void sig(unsigned* c){
  __hip_atomic_fetch_add(c, 1u, __ATOMIC_RELAXED, __HIP_MEMORY_SCOPE_AGENT);
}
__device__ __forceinline__ void waitc(unsigned* c, unsigned v){
  while (__hip_atomic_load(c, __ATOMIC_RELAXED, __HIP_MEMORY_SCOPE_AGENT) < v)
    __builtin_amdgcn_s_sleep(1);
}

// 16B agent-coherent store + drain
__device__ __forceinline__ void stc16_drain(void* p, short8 v){
  asm volatile("global_store_dwordx4 %0, %1, off sc1\n\t"
               "s_waitcnt vmcnt(0)"
               :: "v"((unsigned long long)(uintptr_t)p), "v"(v) : "memory");
}

// sc1 (cache-bypassing) fragment loads for RING mode
__device__ __forceinline__ void load_a16_sc(const unsigned short* base, short8 (&f)[4][4]){
  unsigned long long A0 = (unsigned long long)(uintptr_t)base;
  unsigned long long A1 = A0 + (unsigned long long)(16*NHID*2);
  unsigned long long A2 = A0 + (unsigned long long)(32*NHID*2);
  unsigned long long A3 = A0 + (unsigned long long)(48*NHID*2);
  asm volatile(
    "global_load_dwordx4 %0, %16, off sc1\n\t"
    "global_load_dwordx4 %1, %16, off offset:64 sc1\n\t"
    "global_load_dwordx4 %2, %16, off offset:128 sc1\n\t"
    "global_load_dwordx4 %3, %16, off offset:192 sc1\n\t"
    "global_load_dwordx4 %4, %17, off sc1\n\t"
    "global_load_dwordx4 %5, %17, off offset:64 sc1\n\t"
    "global_load_dwordx4 %6, %17, off offset:128 sc1\n\t"
    "global_load_dwordx4 %7, %17, off offset:192 sc1\n\t"
    "global_load_dwordx4 %8, %18, off sc1\n\t"
    "global_load_dwordx4 %9, %18, off offset:64 sc1\n\t"
    "global_load_dwordx4 %10, %18, off offset:128 sc1\n\t"
    "global_load_dwordx4 %11, %18, off offset:192 sc1\n\t"
    "global_load_dwordx4 %12, %19, off sc1\n\t"
    "global_load_dwordx4 %13, %19, off offset:64 sc1\n\t"
    "global_load_dwordx4 %14, %19, off offset:128 sc1\n\t"
    "global_load_dwordx4 %15, %19, off offset:192 sc1\n\t"
    "s_waitcnt vmcnt(0)"
    : "=&v"(f[0][0]), "=&v"(f[0][1]), "=&v"(f[0][2]), "=&v"(f[0][3]),
      "=&v"(f[1][0]), "=&v"(f[1][1]), "=&v"(f[1][2]), "=&v"(f[1][3]),
      "=&v"(f[2][0]), "=&v"(f[2][1]), "=&v"(f[2][2]), "=&v"(f[2][3]),
      "=&v"(f[3][0]), "=&v"(f[3][1]), "=&v"(f[3][2]), "=&v"(f[3][3])
    : "v"(A0), "v"(A1), "v"(A2), "v"(A3)
    : "memory");
}

// plain cached loads for MONO mode (addresses are write-once -> never stale;
// first WG on an XCD misses to IC, the rest hit the shared XCD L2)
__device__ __forceinline__ void load_a16_plain(const unsigned short* base, short8 (&f)[4][4]){
#pragma unroll
  for (int r=0;r<4;++r){
    const short8* p = (const short8*)(base + (size_t)r*16*NHID);
#pragma unroll
    for (int kt=0;kt<4;++kt) f[r][kt] = p[kt*4];
  }
}

// H [64,1024] bf16 x Wslice^T (regs) -> partials into red (LDS).
template<bool PLAIN>
__device__ __forceinline__ void gemm_phase(const unsigned short* H,
                                           const short8 (&bfr)[3][4],
                                           float* red, int lane, int wid)
{
  const int l15 = lane & 15, q = lane >> 4;
  float4v acc[4][3];
#pragma unroll
  for (int mt=0; mt<4; ++mt)
#pragma unroll
    for (int nt=0; nt<3; ++nt) acc[mt][nt] = (float4v){0.f,0.f,0.f,0.f};

  short8 f[4][4];
  if (PLAIN) load_a16_plain(H + (size_t)l15*NHID + wid*128 + q*8, f);
  else       load_a16_sc   (H + (size_t)l15*NHID + wid*128 + q*8, f);
#pragma unroll
  for (int kt=0; kt<4; ++kt){
#pragma unroll
    for (int nt=0; nt<3; ++nt){
      acc[0][nt] = __builtin_amdgcn_mfma_f32_16x16x32_bf16(f[0][kt], bfr[nt][kt], acc[0][nt],0,0,0);
      acc[1][nt] = __builtin_amdgcn_mfma_f32_16x16x32_bf16(f[1][kt], bfr[nt][kt], acc[1][nt],0,0,0);
      acc[2][nt] = __builtin_amdgcn_mfma_f32_16x16x32_bf16(f[2][kt], bfr[nt][kt], acc[2][nt],0,0,0);
      acc[3][nt] = __builtin_amdgcn_mfma_f32_16x16x32_bf16(f[3][kt], bfr[nt][kt], acc[3][nt],0,0,0);
    }
  }
  if (wid >= 4){
#pragma unroll
    for (int mt=0; mt<4; ++mt)
#pragma unroll
      for (int nt=0; nt<3; ++nt){
        int n = nt*16 + l15, row = mt*16 + q*4;
        *(float4v*)(red + ((wid-4)*48 + n)*RS + row) = acc[mt][nt];
      }
  }
  __syncthreads();
  if (wid < 4){
#pragma unroll
    for (int mt=0; mt<4; ++mt)
#pragma unroll
      for (int nt=0; nt<3; ++nt){
        int n = nt*16 + l15, row = mt*16 + q*4;
        float4v* p = (float4v*)(red + (wid*48 + n)*RS + row);
        float4v v = *p;
        *p = v + acc[mt][nt];
      }
  }
  __syncthreads();
}

__device__ __forceinline__ void load_bfrags(const float* W, const int* rowbase,
                                            short8 (&bfr)[3][4], int lane, int wid)
{
  const int l15 = lane & 15, q = lane >> 4;
#pragma unroll
  for (int nt=0; nt<3; ++nt){
    const float* wp0 = W + (size_t)(rowbase[nt] + l15)*NHID + wid*128 + q*8;
#pragma unroll
    for (int kt=0; kt<4; ++kt){
      const float* wp = wp0 + kt*32;
      short8 fr;
#pragma unroll
      for (int j=0;j<8;++j) fr[j] = (short)f2bf(wp[j]);
      bfr[nt][kt] = fr;
    }
  }
}

template<int MONO>
__global__ __launch_bounds__(NTHR, 2) void mgru_fused(
    const int*   __restrict__ x,    const float* __restrict__ h0,
    const float* __restrict__ emb,
    const float* __restrict__ Wih0, const float* __restrict__ Whh0,
    const float* __restrict__ bih0, const float* __restrict__ bhh0,
    const float* __restrict__ Wih1, const float* __restrict__ Whh1,
    const float* __restrict__ bih1, const float* __restrict__ bhh1,
    const float* __restrict__ gamma, const float* __restrict__ beta,
    const float* __restrict__ Wout, const float* __restrict__ bout,
    float* __restrict__ out, char* ws)
{
  __shared__ __align__(16) char smem[LDS_BYTES];
  float* red = (float*)smem;

  unsigned* f0  = (unsigned*)(ws + OFF_F0);
  unsigned* f2  = (unsigned*)(ws + OFF_F2);
  unsigned* fin = (unsigned*)(ws + OFF_FIN);
  unsigned short* y0b   = (unsigned short*)(ws + (MONO ? M_OFF_Y0 : R_OFF_Y0));
  unsigned short* y1    = (unsigned short*)(ws + (MONO ? M_OFF_Y1 : R_OFF_Y1));
  unsigned short* h1r   = MONO ? (unsigned short*)(ws + M_OFF_H1I)
                               : (unsigned short*)(ws + R_OFF_H1);
  float*          T0    = (float*)(ws + (MONO ? M_OFF_T0 : R_OFF_T0));
  float*          stats = (float*)(ws + (MONO ? M_OFF_ST : R_OFF_ST));

  const int tid  = threadIdx.x;
  const int lane = tid & 63;
  const int wid  = tid >> 6;
  const int wg   = blockIdx.x;
  const int role = (wg < 64) ? 0 : 2;
  const int sub  = (role==0) ? wg : wg-64;

  const int ch0 = sub*16;
  const int cg  = tid >> 6;
  const int gb  = tid & 63;
  int rowbase[3] = {ch0, NHID + ch0, 2*NHID + ch0};

  if (MONO){
    // one-time acquire: invalidate any stale L1/L2 lines from a previous launch
    if (tid == 0) __threadfence();
    __syncthreads();
  }

  if (role == 0){
    // ================= layer-0 recurrence =================
    short8 bfr[3][4];
    float hprev[8] = {0,0,0,0,0,0,0,0};
    float br[8], bz[8], bn[8];
    if (tid < 128){
      short8 pk;
#pragma unroll
      for (int j=0;j<8;++j){
        int c = ch0 + cg*8 + j;
        hprev[j] = h0[(size_t)gb*NHID + c];
        br[j] = bhh0[c]; bz[j] = bhh0[NHID + c]; bn[j] = bhh0[2*NHID + c];
        pk[j] = (short)f2bf(hprev[j]);
      }
      // y0(-1): MONO slot 0, RING slot 3
      size_t slot = MONO ? 0 : 3;
      stc16_drain(y0b + slot*SL + (size_t)gb*NHID + ch0 + cg*8, pk);
    }
    __syncthreads();
    if (tid == 0) setflag(f0 + (size_t)wg*16, 1u);

    // T0 slice (WG-private, plain cached)
    for (int e = tid; e < NVOC*48; e += NTHR){
      int v = e / 48, n = e - v*48;
      int g = (n<16) ? (ch0+n) : (n<32 ? (NHID+ch0+n-16) : (2*NHID+ch0+n-32));
      const float4v* e4 = (const float4v*)(emb  + (size_t)v*NHID);
      const float4v* w4 = (const float4v*)(Wih0 + (size_t)g*NHID);
      float acc = 0.f;
      for (int k=0;k<NHID/4;++k){
        float4v a = e4[k], bb = w4[k];
        acc += a[0]*bb[0] + a[1]*bb[1] + a[2]*bb[2] + a[3]*bb[3];
      }
      T0[(size_t)v*3*NHID + g] = acc + bih0[g];
    }
    load_bfrags(Whh0, rowbase, bfr, lane, wid);
    __syncthreads();

    for (int t = 0; t < NSEQ; ++t){
      if (MONO){
        if (wid == 0) wait1(f0, t+1, lane);              // y0(t-1) ready; no WAR
      } else {
        if (wid == 0) wait2(f0, t+1, f2, t-2, lane);     // + ring WAR
      }
      __syncthreads();
      const unsigned short* src = MONO ? (y0b + (size_t)t*SL)
                                       : (y0b + (size_t)((t+3)&3)*SL);
      gemm_phase<MONO!=0>(src, bfr, red, lane, wid);
      if (tid < 128){
        int tok = x[(size_t)gb*NSEQ + t];
        const float* tr = T0 + (size_t)tok*3*NHID + ch0 + cg*8;
        short8 pk;
#pragma unroll
        for (int j=0;j<8;++j){
          float hr = br[j], hz = bz[j], hn = bn[j];
#pragma unroll
          for (int w=0;w<4;++w){
            hr += red[(w*48 +      cg*8 + j)*RS + gb];
            hz += red[(w*48 + 16 + cg*8 + j)*RS + gb];
            hn += red[(w*48 + 32 + cg*8 + j)*RS + gb];
          }
          float r = sigm(tr[j] + hr);
          float z = sigm(tr[NHID + j] + hz);
          float n = tanh_f(tr[2*NHID + j] + r*hn);
          float hnv = (1.f - z)*n + z*hprev[j];
          hprev[j] = hnv;
          pk[j] = (short)f2bf(hnv);
        }
        size_t slot = MONO ? (size_t)(t+1) : (size_t)(t&3);
        stc16_drain(y0b + slot*SL + (size_t)gb*NHID + ch0 + cg*8, pk);
      }
      __syncthreads();
      if (tid == 0) setflag(f0 + (size_t)wg*16, (unsigned)(t+2));
    }

  } else {
    // ================= layer-1 recurrence + xg + BN stats =================
    short8 bfrH[3][4], wf[3][4];
    load_bfrags(Whh1, rowbase, bfrH, lane, wid);
    load_bfrags(Wih1, rowbase, wf,   lane, wid);

    float hprev[8] = {0,0,0,0,0,0,0,0};
    float s1[8] = {0,0,0,0,0,0,0,0}, s2[8] = {0,0,0,0,0,0,0,0};
    if (tid < 128){
      short8 pk;
#pragma unroll
      for (int j=0;j<8;++j){
        hprev[j] = h0[(size_t)NB*NHID + (size_t)gb*NHID + ch0 + cg*8 + j];
        pk[j] = (short)f2bf(hprev[j]);
      }
      // h1(-1): MONO -> h1init slot, RING -> ring slot 1
      size_t off = MONO ? 0 : (size_t)SL;
      stc16_drain(h1r + off + (size_t)gb*NHID + ch0 + cg*8, pk);
    }
    __syncthreads();
    if (tid == 0) setflag(f2 + (size_t)sub*16, 1u);

    float* hp = (float*)(smem + LDS_HP_OFF) + (size_t)tid*25;

    for (int t = 0; t < NSEQ; ++t){
      if (wid == 0) wait1(f2, t+1, lane);   // h1(t-1) written by all role2 WGs
      __syncthreads();
      const unsigned short* hsrc;
      if (MONO) hsrc = (t == 0) ? h1r : (y1 + (size_t)(t-1)*SL);
      else      hsrc = h1r + (size_t)((t+1)&1)*SL;
      gemm_phase<MONO!=0>(hsrc, bfrH, red, lane, wid);
      if (tid < 128){
#pragma unroll
        for (int j=0;j<8;++j){
          int c = ch0 + cg*8 + j;
          float hr = bhh1[c], hz = bhh1[NHID + c], hn = bhh1[2*NHID + c];
#pragma unroll
          for (int w=0;w<4;++w){
            hr += red[(w*48 +      cg*8 + j)*RS + gb];
            hz += red[(w*48 + 16 + cg*8 + j)*RS + gb];
            hn += red[(w*48 + 32 + cg*8 + j)*RS + gb];
          }
          hp[j] = hr; hp[8+j] = hz; hp[16+j] = hn;
        }
      }
      if (wid == 0) wait1(f0, t+2, lane);   // y0(t) ready
      __syncthreads();
      const unsigned short* xsrc = MONO ? (y0b + (size_t)(t+1)*SL)
                                        : (y0b + (size_t)(t&3)*SL);
      gemm_phase<MONO!=0>(xsrc, wf, red, lane, wid);
      if (tid < 128){
        short8 pk;
#pragma unroll
        for (int j=0;j<8;++j){
          int c = ch0 + cg*8 + j;
          float xr = bih1[c], xz = bih1[NHID + c], xn = bih1[2*NHID + c];
#pragma unroll
          for (int w=0;w<4;++w){
            xr += red[(w*48 +      cg*8 + j)*RS + gb];
            xz += red[(w*48 + 16 + cg*8 + j)*RS + gb];
            xn += red[(w*48 + 32 + cg*8 + j)*RS + gb];
          }
          float r = sigm(xr + hp[j]);
          float z = sigm(xz + hp[8+j]);
          float n = tanh_f(xn + r*hp[16+j]);
          float hnv = (1.f - z)*n + z*hprev[j];
          hprev[j] = hnv;
          unsigned short hb = f2bf(hnv);
          pk[j] = (short)hb;
          float hq = bf2f(hb);               // BN stats from stored bf16
          s1[j] += hq; s2[j] += hq*hq;
        }
        if (MONO){
          // y1(t) doubles as h1(t): single coherent store
          stc16_drain(y1 + (size_t)t*SL + (size_t)gb*NHID + ch0 + cg*8, pk);
        } else {
          *(short8*)(y1 + (size_t)t*SL + (size_t)gb*NHID + ch0 + cg*8) = pk;  // plain
          stc16_drain(h1r + (size_t)(t&1)*SL + (size_t)gb*NHID + ch0 + cg*8, pk);
        }
      }
      __syncthreads();
      if (tid == 0) setflag(f2 + (size_t)sub*16, (unsigned)(t+2));
    }

    // BN stats
    float* sb = (float*)smem;
    __syncthreads();
    if (tid < 128){
#pragma unroll
      for (int j=0;j<8;++j) sb[(cg*8 + j)*64 + gb] = s1[j];
    }
    __syncthreads();
    if (tid < 16){
      float a = 0.f;
      for (int i=0;i<64;++i) a += sb[tid*64 + i];
      stats[ch0 + tid] = a;
    }
    __syncthreads();
    if (tid < 128){
#pragma unroll
      for (int j=0;j<8;++j) sb[(cg*8 + j)*64 + gb] = s2[j];
    }
    __syncthreads();
    if (tid < 16){
      float a = 0.f;
      for (int i=0;i<64;++i) a += sb[tid*64 + i];
      stats[NHID + ch0 + tid] = a;
    }
  }

  // ======== fin barrier with ONE wbL2/inv fence pair per WG ========
  __syncthreads();
  if (tid == 0){
    __threadfence();          // release: writeback dirty L2 (y1/stats)
    sig(fin);
    waitc(fin, NBLK);
    __threadfence();          // acquire
  }
  __syncthreads();

  // ================= epilogue: fold BN into Wout, GEMM -> out =================
  const float inv_n = 1.f/32768.f;
  const int l15 = lane & 15, q = lane >> 4;

  float* bpart    = (float*)smem;
  float* bprime_l = (float*)(smem + 2048);
  {
    int v = tid >> 4, k0 = tid & 15;
    float partial = 0.f;
    if (v < NVOC){
      for (int k = k0; k < NHID; k += 16){
        float mu  = stats[k]*inv_n;
        float var = stats[NHID+k]*inv_n - mu*mu;
        float sc  = gamma[k]*rsqrtf(var + EPSV);
        partial += (beta[k] - mu*sc) * Wout[(size_t)v*NHID + k];
      }
    }
    bpart[tid] = partial;
  }
  __syncthreads();
  if (tid < 32){
    float bpv = 0.f;
    for (int j=0;j<16;++j) bpv += bpart[tid*16 + j];
    bprime_l[tid] = (tid < NVOC) ? (bpv + bout[tid]) : 0.f;
  }
  __syncthreads();
  float bp_a = bprime_l[l15];
  float bp_b = (l15 < 15) ? bprime_l[16 + l15] : 0.f;
  __syncthreads();

  unsigned short* wsc = (unsigned short*)smem;   // [31][1032] bf16
  for (int e = tid; e < NVOC*1032; e += NTHR){
    int v = e / 1032, k = e - v*1032;
    float val = 0.f;
    if (k < NHID){
      float mu  = stats[k]*inv_n;
      float var = stats[NHID+k]*inv_n - mu*mu;
      float sc  = gamma[k]*rsqrtf(var + EPSV);
      val = Wout[(size_t)v*NHID + k] * sc;
    }
    wsc[e] = f2bf(val);
  }
  __syncthreads();

  int wglob = wg*8 + wid;
  if ((wglob & 1) == 0){
    int J = wglob >> 1;         // 0..511
    float4v acc[4][2];
#pragma unroll
    for (int mt=0;mt<4;++mt){ acc[mt][0] = (float4v){0,0,0,0}; acc[mt][1] = (float4v){0,0,0,0}; }
    const unsigned short* abase = y1 + (size_t)(J*64 + l15)*NHID + q*8;
    const short8 zero8 = (short8){0,0,0,0,0,0,0,0};
#pragma unroll 4
    for (int kt=0; kt<32; ++kt){
      short8 bv0 = *(const short8*)(wsc + (size_t)l15*1032 + kt*32 + q*8);
      short8 bv1 = (l15 < 15) ? *(const short8*)(wsc + (size_t)(16+l15)*1032 + kt*32 + q*8) : zero8;
      short8 a0 = *(const short8*)(abase + (size_t)kt*32);
      short8 a1 = *(const short8*)(abase + 16*NHID + (size_t)kt*32);
      short8 a2 = *(const short8*)(abase + 32*NHID + (size_t)kt*32);
      short8 a3 = *(const short8*)(abase + 48*NHID + (size_t)kt*32);
      acc[0][0] = __builtin_amdgcn_mfma_f32_16x16x32_bf16(a0, bv0, acc[0][0],0,0,0);
      acc[1][0] = __builtin_amdgcn_mfma_f32_16x16x32_bf16(a1, bv0, acc[1][0],0,0,0);
      acc[2][0] = __builtin_amdgcn_mfma_f32_16x16x32_bf16(a2, bv0, acc[2][0],0,0,0);
      acc[3][0] = __builtin_amdgcn_mfma_f32_16x16x32_bf16(a3, bv0, acc[3][0],0,0,0);
      acc[0][1] = __builtin_amdgcn_mfma_f32_16x16x32_bf16(a0, bv1, acc[0][1],0,0,0);
      acc[1][1] = __builtin_amdgcn_mfma_f32_16x16x32_bf16(a1, bv1, acc[1][1],0,0,0);
      acc[2][1] = __builtin_amdgcn_mfma_f32_16x16x32_bf16(a2, bv1, acc[2][1],0,0,0);
      acc[3][1] = __builtin_amdgcn_mfma_f32_16x16x32_bf16(a3, bv1, acc[3][1],0,0,0);
    }
#pragma unroll
    for (int mt=0;mt<4;++mt){
#pragma unroll
      for (int nt=0;nt<2;++nt){
        int v = nt*16 + l15;
        if (v < NVOC){
          float bpv = (nt==0) ? bp_a : bp_b;
          int r0 = J*64 + mt*16 + q*4;
#pragma unroll
          for (int i2=0;i2<4;++i2){
            int r = r0 + i2;
            int b = r & 63, tt = r >> 6;
            out[(size_t)(b*NSEQ + tt)*NVOC + v] = acc[mt][nt][i2] + bpv;
          }
        }
      }
    }
  }
}

extern "C" void kernel_launch(void* const* d_in, const int* in_sizes, int n_in,
                              void* d_out, int out_size, void* d_ws, size_t ws_size,
                              hipStream_t stream) {
  (void)in_sizes; (void)n_in; (void)out_size;
  hipMemsetAsync(d_ws, 0, CNT_BYTES, stream);
  // ws_size is fixed per-problem -> same branch every call (graph-safe)
  if (ws_size >= (size_t)NEED_MONO){
    mgru_fused<1><<<dim3(NBLK), dim3(NTHR), 0, stream>>>(
        (const int*)d_in[0],  (const float*)d_in[1],  (const float*)d_in[2],
        (const float*)d_in[3], (const float*)d_in[4], (const float*)d_in[5],
        (const float*)d_in[6], (const float*)d_in[7], (const float*)d_in[8],
        (const float*)d_in[9], (const float*)d_in[10], (const float*)d_in[11],
        (const float*)d_in[12], (const float*)d_in[13], (const float*)d_in[14],
        (float*)d_out, (char*)d_ws);
  } else {
    mgru_fused<0><<<dim3(NBLK), dim3(NTHR), 0, stream>>>(
        (const int*)d_in[0],  (const float*)d_in[1],  (const float*)d_in[2],
        (const float*)d_in[3], (const float*)d_in[4], (const float*)d_in[5],
        (const float*)d_in[6], (const float*)d_in[7], (const float*)d_in[8],
        (const float*)d_in[9], (const float*)d_in[10], (const float*)d_in[11],
        (const float*)d_in[12], (const float*)d_in[13], (const float*)d_in[14],
        (float*)d_out, (char*)d_ws);
  }
}